// Round 11
// baseline (18637.482 us; speedup 1.0000x reference)
//
#include <hip/hip_runtime.h>
#include <hip/hip_fp16.h>

#define T_STEPS 2048
#define B_SZ 128
#define I_SZ 10
#define H_SZ 512

#define NGRP 8            // batch groups (16 rows each) = 8 independent chains
#define GWG 8             // wgs per group
#define NWG 32            // 4 pairs x 8 wgs; each wg runs TWO chains (groups 2p,2p+1)
#define BSLICE 16         // batch rows per group
#define WCOL 64           // hidden cols per wg
#define NTHR 512

typedef _Float16 f16x8 __attribute__((ext_vector_type(8)));
typedef float f32x4 __attribute__((ext_vector_type(4)));
typedef float f32x2 __attribute__((ext_vector_type(2)));
typedef unsigned u32x4 __attribute__((ext_vector_type(4)));
typedef unsigned u32x2 __attribute__((ext_vector_type(2)));
typedef unsigned long long u64t;

// Tagged h buffers: [2][NGRP][BSLICE][H/2] u64, u64 = (tag << 32) | 2xfp16.
// MUST be zeroed before every persistent launch (stale tags / 0xAA poison
// would satisfy the tag check).
__global__ void clear_hbuf_kernel(u64t* p) {
    const int i = blockIdx.x * 256 + threadIdx.x;   // 16384 threads
    #pragma unroll
    for (int k = 0; k < 4; ++k)
        __hip_atomic_store(p + i + k * 16384, 0ull,
                           __ATOMIC_RELAXED, __HIP_MEMORY_SCOPE_AGENT);
}

// One LSTM step for one chain (group g). R10-proven protocol:
//   tagged-payload staging (coalesced 1KB/instruction), own-tile shortcut,
//   MFMA from LDS, gate exchange, update, fire-and-forget tagged publish.
// Two __syncthreads per call. All control flow wg-uniform.
__device__ __forceinline__ void lstm_phase(
    const int t, const int g, const bool do_publish,
    u64t* __restrict__ hbuf,
    _Float16 (* __restrict__ h_stage)[520],
    float (* __restrict__ lds_g)[17],
    const f16x8 (&wf)[2][16], const float (&wih)[2][I_SZ],
    const float (&bias)[2],
    const float* __restrict__ x,
    float& c0, float& c1, float& h0, float& h1)
{
    const int tid  = threadIdx.x;
    const int wid  = tid >> 6;
    const int lane = tid & 63;
    const int fr_col = lane & 15;
    const int fr_kg  = lane >> 4;
    const int wgin = blockIdx.x & 7;

    // -- x_t @ W_ih^T + bias (h-independent)
    f32x4 acc[2];
    #pragma unroll
    for (int r = 0; r < 4; ++r) {
        const int grow = g * BSLICE + fr_kg * 4 + r;
        const f32x2* xp = (const f32x2*)(x + ((size_t)t * B_SZ + grow) * I_SZ);
        const f32x2 a0 = xp[0], a1 = xp[1], a2 = xp[2], a3 = xp[3], a4 = xp[4];
        #pragma unroll
        for (int f = 0; f < 2; ++f) {
            float s = bias[f];
            s += a0.x*wih[f][0] + a0.y*wih[f][1] + a1.x*wih[f][2] + a1.y*wih[f][3]
               + a2.x*wih[f][4] + a2.y*wih[f][5] + a3.x*wih[f][6] + a3.y*wih[f][7]
               + a4.x*wih[f][8] + a4.y*wih[f][9];
            acc[f][r] = s;
        }
    }

    // -- tagged coalesced staging (retry only stale lanes; own pieces skip)
    {
        const u64t* hb = hbuf + ((size_t)(t & 1) * NGRP + g) * (BSLICE * 256);
        const char* sp = (const char*)hb + wid * 4096 + lane * 16;
        const unsigned tgt = (unsigned)(t + 1);
        int srow[4], spr[4];
        bool own[4];
        #pragma unroll
        for (int j = 0; j < 4; ++j) {
            const int q = wid * 512 + j * 128 + lane * 2;
            srow[j] = q >> 8;
            spr[j]  = q & 255;
            own[j]  = ((spr[j] >> 5) == wgin);
        }
        u32x4 q0, q1, q2, q3;
        bool done = false;
        for (;;) {
            if (!done) {
                asm volatile(
                    "global_load_dwordx4 %0, %4, off sc0 sc1\n\t"
                    "global_load_dwordx4 %1, %4, off offset:1024 sc0 sc1\n\t"
                    "global_load_dwordx4 %2, %4, off offset:2048 sc0 sc1\n\t"
                    "global_load_dwordx4 %3, %4, off offset:3072 sc0 sc1\n\t"
                    "s_waitcnt vmcnt(0)"
                    : "=&v"(q0), "=&v"(q1), "=&v"(q2), "=&v"(q3)
                    : "v"(sp) : "memory");
                done = (own[0] || (q0.y >= tgt && q0.w >= tgt)) &&
                       (own[1] || (q1.y >= tgt && q1.w >= tgt)) &&
                       (own[2] || (q2.y >= tgt && q2.w >= tgt)) &&
                       (own[3] || (q3.y >= tgt && q3.w >= tgt));
            }
            if (__all(done)) break;
            __builtin_amdgcn_s_sleep(1);
        }
        if (!own[0]) *(u32x2*)&h_stage[srow[0]][spr[0] * 2] = (u32x2){q0.x, q0.z};
        if (!own[1]) *(u32x2*)&h_stage[srow[1]][spr[1] * 2] = (u32x2){q1.x, q1.z};
        if (!own[2]) *(u32x2*)&h_stage[srow[2]][spr[2] * 2] = (u32x2){q2.x, q2.z};
        if (!own[3]) *(u32x2*)&h_stage[srow[3]][spr[3] * 2] = (u32x2){q3.x, q3.z};
    }
    __syncthreads();   // B1: staging visible

    // -- 16 K-chunks: ds_read A-frag, 2 MFMAs each
    #pragma unroll
    for (int c = 0; c < 16; ++c) {
        const f16x8 a = *(const f16x8*)&h_stage[fr_col][c * 32 + fr_kg * 8];
        acc[0] = __builtin_amdgcn_mfma_f32_16x16x32_f16(a, wf[0][c], acc[0], 0, 0, 0);
        acc[1] = __builtin_amdgcn_mfma_f32_16x16x32_f16(a, wf[1][c], acc[1], 0, 0, 0);
    }

    // -- gate pre-activations -> LDS
    #pragma unroll
    for (int f = 0; f < 2; ++f) {
        const int gcL = wid * 32 + f * 16 + fr_col;
        #pragma unroll
        for (int r = 0; r < 4; ++r)
            lds_g[gcL][fr_kg * 4 + r] = acc[f][r];
    }
    __syncthreads();   // B2: gates visible; fences all h_stage reads

    // -- c/h update for 2 owned cells; tagged publish + own-tile shortcut
    {
        const int orow = tid >> 5;
        const int cl   = 2 * (tid & 31);
        const int ocol = wgin * WCOL + cl;
        const size_t my_q = (size_t)orow * 256 + ((ocol) >> 1);

        const float i0 = lds_g[0 * WCOL + cl][orow],     f0 = lds_g[1 * WCOL + cl][orow];
        const float g0 = lds_g[2 * WCOL + cl][orow],     o0 = lds_g[3 * WCOL + cl][orow];
        const float i1 = lds_g[0 * WCOL + cl + 1][orow], f1 = lds_g[1 * WCOL + cl + 1][orow];
        const float g1 = lds_g[2 * WCOL + cl + 1][orow], o1 = lds_g[3 * WCOL + cl + 1][orow];

        const float ig0 = 1.f / (1.f + __expf(-i0));
        const float fg0 = 1.f / (1.f + __expf(-f0));
        const float eg0 = __expf(-2.f * g0);
        const float tg0 = (1.f - eg0) / (1.f + eg0);
        const float og0 = 1.f / (1.f + __expf(-o0));
        const float ig1 = 1.f / (1.f + __expf(-i1));
        const float fg1 = 1.f / (1.f + __expf(-f1));
        const float eg1 = __expf(-2.f * g1);
        const float tg1 = (1.f - eg1) / (1.f + eg1);
        const float og1 = 1.f / (1.f + __expf(-o1));

        c0 = fg0 * c0 + ig0 * tg0;
        c1 = fg1 * c1 + ig1 * tg1;
        const float e0 = __expf(-2.f * c0), e1 = __expf(-2.f * c1);
        h0 = og0 * (1.f - e0) / (1.f + e0);
        h1 = og1 * (1.f - e1) / (1.f + e1);

        if (do_publish) {
            u64t* hbn = hbuf + ((size_t)((t + 1) & 1) * NGRP + g) * (BSLICE * 256);
            union { _Float16 hp[2]; unsigned u; } pk;
            pk.hp[0] = (_Float16)h0; pk.hp[1] = (_Float16)h1;
            __hip_atomic_store(hbn + my_q,
                               ((u64t)(unsigned)(t + 2) << 32) | pk.u,
                               __ATOMIC_RELAXED, __HIP_MEMORY_SCOPE_AGENT);
            *(unsigned*)&h_stage[orow][ocol] = pk.u;   // own-tile shortcut
        }
    }
}

// Persistent LSTM: each wg runs TWO independent batch-group chains,
// phase-alternated, so each chain's publish->poll latency is hidden behind
// the other chain's compute. Weights (registers) are shared by both chains.
//
// Double-buffer safety per chain (unchanged from R9/R10, groups disjoint):
// publish at end of step s writes tag s+2 into buf[(s+1)&1]; overwriting
// buf[p] requires all wgs of the group consumed the previous tags of buf[p].
// Deadlock-free: phases strictly ordered (A then B) in every iteration for
// every wg of the pair; groups of different pairs never interact.
__global__ __launch_bounds__(NTHR, 2) void lstm_persistent(
    const float* __restrict__ x,     // [T,B,I]
    const float* __restrict__ hx,    // [B,H]
    const float* __restrict__ cx,    // [B,H]
    const float* __restrict__ W_ih,  // [4H,I]
    const float* __restrict__ W_hh,  // [4H,H]
    const float* __restrict__ b_ih,  // [4H]
    const float* __restrict__ b_hh,  // [4H]
    float* __restrict__ out,         // [3*B*H] = h, h, c
    u64t* hbuf)                      // [2][NGRP][BSLICE][H/2] tagged
{
    __shared__ _Float16 h_stageA[BSLICE][520];
    __shared__ _Float16 h_stageB[BSLICE][520];
    __shared__ float lds_gA[4 * WCOL][17];
    __shared__ float lds_gB[4 * WCOL][17];

    const int wg   = blockIdx.x;
    const int pr   = wg >> 3;          // pair 0..3
    const int wgin = wg & 7;           // wg within group 0..7
    const int gA   = 2 * pr;
    const int gB   = 2 * pr + 1;
    const int tid  = threadIdx.x;
    const int wid  = tid >> 6;
    const int lane = tid & 63;
    const int fr_col = lane & 15;
    const int fr_kg  = lane >> 4;

    // ---- W_hh B-fragments (shared by both chains): 2 frags x 16 K-chunks
    f16x8 wf[2][16];
    float wih[2][I_SZ], bias[2];
    #pragma unroll
    for (int f = 0; f < 2; ++f) {
        const int gcL = wid * 32 + f * 16 + fr_col;               // 0..255
        const int wr  = (gcL >> 6) * H_SZ + wgin * WCOL + (gcL & 63);
        #pragma unroll
        for (int c = 0; c < 16; ++c) {
            const float* p = W_hh + (size_t)wr * H_SZ + c * 32 + fr_kg * 8;
            f16x8 w;
            #pragma unroll
            for (int e = 0; e < 8; ++e) w[e] = (_Float16)p[e];
            wf[f][c] = w;
        }
        #pragma unroll
        for (int i = 0; i < I_SZ; ++i) wih[f][i] = W_ih[wr * I_SZ + i];
        bias[f] = b_ih[wr] + b_hh[wr];
    }

    // ---- owned cells (same (row,col) slot in each chain's group)
    const int orow  = tid >> 5;
    const int ocol  = wgin * WCOL + 2 * (tid & 31);
    const int gbrowA = gA * BSLICE + orow;
    const int gbrowB = gB * BSLICE + orow;
    const size_t my_q = (size_t)orow * 256 + (ocol >> 1);

    float cA0 = cx[gbrowA * H_SZ + ocol], cA1 = cx[gbrowA * H_SZ + ocol + 1];
    float hA0 = hx[gbrowA * H_SZ + ocol], hA1 = hx[gbrowA * H_SZ + ocol + 1];
    float cB0 = cx[gbrowB * H_SZ + ocol], cB1 = cx[gbrowB * H_SZ + ocol + 1];
    float hB0 = hx[gbrowB * H_SZ + ocol], hB1 = hx[gbrowB * H_SZ + ocol + 1];

    // ---- publish h(0) with tag 1 (both chains) + own-tile LDS writes
    {
        union { _Float16 hp[2]; unsigned u; } pk;
        pk.hp[0] = (_Float16)hA0; pk.hp[1] = (_Float16)hA1;
        __hip_atomic_store(hbuf + (size_t)gA * (BSLICE * 256) + my_q,
                           ((u64t)1u << 32) | pk.u,
                           __ATOMIC_RELAXED, __HIP_MEMORY_SCOPE_AGENT);
        *(unsigned*)&h_stageA[orow][ocol] = pk.u;
        pk.hp[0] = (_Float16)hB0; pk.hp[1] = (_Float16)hB1;
        __hip_atomic_store(hbuf + (size_t)gB * (BSLICE * 256) + my_q,
                           ((u64t)1u << 32) | pk.u,
                           __ATOMIC_RELAXED, __HIP_MEMORY_SCOPE_AGENT);
        *(unsigned*)&h_stageB[orow][ocol] = pk.u;
    }

    #pragma unroll 1
    for (int t = 0; t < T_STEPS; ++t) {
        const bool pub = (t < T_STEPS - 1);
        lstm_phase(t, gA, pub, hbuf, h_stageA, lds_gA, wf, wih, bias, x,
                   cA0, cA1, hA0, hA1);
        lstm_phase(t, gB, pub, hbuf, h_stageB, lds_gB, wf, wih, bias, x,
                   cB0, cB1, hB0, hB1);
    }

    // ---- outputs: (h, h, c), each [B,H] f32, both chains
    out[gbrowA * H_SZ + ocol]                       = hA0;
    out[gbrowA * H_SZ + ocol + 1]                   = hA1;
    out[B_SZ * H_SZ + gbrowA * H_SZ + ocol]         = hA0;
    out[B_SZ * H_SZ + gbrowA * H_SZ + ocol + 1]     = hA1;
    out[2 * B_SZ * H_SZ + gbrowA * H_SZ + ocol]     = cA0;
    out[2 * B_SZ * H_SZ + gbrowA * H_SZ + ocol + 1] = cA1;

    out[gbrowB * H_SZ + ocol]                       = hB0;
    out[gbrowB * H_SZ + ocol + 1]                   = hB1;
    out[B_SZ * H_SZ + gbrowB * H_SZ + ocol]         = hB0;
    out[B_SZ * H_SZ + gbrowB * H_SZ + ocol + 1]     = hB1;
    out[2 * B_SZ * H_SZ + gbrowB * H_SZ + ocol]     = cB0;
    out[2 * B_SZ * H_SZ + gbrowB * H_SZ + ocol + 1] = cB1;
}

extern "C" void kernel_launch(void* const* d_in, const int* in_sizes, int n_in,
                              void* d_out, int out_size, void* d_ws, size_t ws_size,
                              hipStream_t stream) {
    const float* x    = (const float*)d_in[0];
    const float* hx   = (const float*)d_in[1];
    const float* cx   = (const float*)d_in[2];
    const float* W_ih = (const float*)d_in[3];
    const float* W_hh = (const float*)d_in[4];
    const float* b_ih = (const float*)d_in[5];
    const float* b_hh = (const float*)d_in[6];
    float* out = (float*)d_out;

    // ws: [0, 512KB) tagged h double-buffer
    u64t* hbuf = (u64t*)d_ws;

    clear_hbuf_kernel<<<64, 256, 0, stream>>>(hbuf);
    lstm_persistent<<<NWG, NTHR, 0, stream>>>(x, hx, cx, W_ih, W_hh, b_ih, b_hh,
                                              out, hbuf);
}

// Round 12
// 10174.702 us; speedup vs baseline: 1.8317x; 1.8317x over previous
//
#include <hip/hip_runtime.h>
#include <hip/hip_fp16.h>

#define T_STEPS 2048
#define B_SZ 128
#define I_SZ 10
#define H_SZ 512

#define NGRP 8            // batch groups (16 rows each)
#define GWG 8             // wgs per group
#define NWG (NGRP * GWG)  // 64 workgroups
#define BSLICE 16         // batch rows per group
#define WCOL 64           // hidden cols per wg
#define NTHR 512

typedef _Float16 f16x8 __attribute__((ext_vector_type(8)));
typedef float f32x4 __attribute__((ext_vector_type(4)));
typedef float f32x2 __attribute__((ext_vector_type(2)));
typedef unsigned u32x4 __attribute__((ext_vector_type(4)));

// flags: u32[NGRP][64] — one per (wg, wave). Cleared every launch
// (replay/poison safety).
__global__ void clear_flags_kernel(unsigned* p) {
    const int i = blockIdx.x * 256 + threadIdx.x;
    if (i < NGRP * 64)
        __hip_atomic_store(p + i, 0u, __ATOMIC_RELAXED, __HIP_MEMORY_SCOPE_AGENT);
}

// Persistent LSTM. R8-proven protocol with per-wave release and parallel poll:
//
//   8 independent batch-groups x 8 wgs; wg owns 64 hidden cols (all 4 gates,
//   full K) of its group's 16 batch rows. W_hh fp16 register-resident.
//
//   publish (per WAVE): h stores (u32 relaxed agent = sc0 sc1, coherent at
//   LLC) -> s_waitcnt vmcnt(0) (per-wave) -> own flag store. No release
//   barrier, no wg-wide drain.
//   consume (per WAVE): poll all 64 group flags (4 cache lines) -> coalesced
//   staging of this wave's 2KB of the 16KB h-slice (1KB contiguous per
//   instruction) -> B1 -> MFMA from LDS.
//
// Double-buffer safety: wave flag = t+2 implies (program order) that wave
// completed its step-t staging reads of buf[t&1] and drained its h(t+1)
// stores. A producer overwrites buf[t&1] (with h(t+2)) only at end of its
// step t+1, which it reaches only after poll(t+1) saw ALL 64 flags >= t+2,
// i.e. every wave everywhere finished step-t reads of buf[t&1].
//
// LDS hazards: h_stage reads (MFMA, pre-B2) vs staging writes (t+1, pre-B1):
// separated by B2(t); lds_g reads (post-B2) vs writes (t+1, post-B1):
// separated by B1(t+1). Two barriers per step suffice.
__global__ __launch_bounds__(NTHR, 2) void lstm_persistent(
    const float* __restrict__ x,     // [T,B,I]
    const float* __restrict__ hx,    // [B,H]
    const float* __restrict__ cx,    // [B,H]
    const float* __restrict__ W_ih,  // [4H,I]
    const float* __restrict__ W_hh,  // [4H,H]
    const float* __restrict__ b_ih,  // [4H]
    const float* __restrict__ b_hh,  // [4H]
    float* __restrict__ out,         // [3*B*H] = h, h, c
    unsigned* flags,                 // [NGRP][64]
    _Float16* hbuf)                  // [2][NGRP][BSLICE][H]
{
    __shared__ _Float16 h_stage[BSLICE][520];   // +8 fp16 pad per row
    __shared__ float lds_g[4 * WCOL][17];       // [gate*64+col][row], padded

    const int wg   = blockIdx.x;
    const int g    = wg >> 3;          // batch group 0..7
    const int wgin = wg & 7;           // wg within group 0..7
    const int tid  = threadIdx.x;
    const int wid  = tid >> 6;         // wave 0..7
    const int lane = tid & 63;
    const int fr_col = lane & 15;
    const int fr_kg  = lane >> 4;      // 0..3

    // ---- this wave's two gate-column fragments (wg covers 256 gate-cols)
    int gcL[2], wr[2];
    #pragma unroll
    for (int f = 0; f < 2; ++f) {
        gcL[f] = wid * 32 + f * 16 + fr_col;              // 0..255
        wr[f]  = (gcL[f] >> 6) * H_SZ + wgin * WCOL + (gcL[f] & 63);
    }

    // ---- W_hh B-fragments: 2 frags x 16 K-chunks, fp16 register-resident
    f16x8 wf[2][16];
    #pragma unroll
    for (int f = 0; f < 2; ++f)
        #pragma unroll
        for (int c = 0; c < 16; ++c) {
            const float* p = W_hh + (size_t)wr[f] * H_SZ + c * 32 + fr_kg * 8;
            f16x8 w;
            #pragma unroll
            for (int e = 0; e < 8; ++e) w[e] = (_Float16)p[e];
            wf[f][c] = w;
        }

    // ---- W_ih rows + combined bias
    float wih[2][I_SZ], bias[2];
    #pragma unroll
    for (int f = 0; f < 2; ++f) {
        #pragma unroll
        for (int i = 0; i < I_SZ; ++i) wih[f][i] = W_ih[wr[f] * I_SZ + i];
        bias[f] = b_ih[wr[f]] + b_hh[wr[f]];
    }

    // ---- owned cells: 2 adjacent per thread (16 rows x 64 cols per wg)
    const int orow  = tid >> 5;                    // 0..15
    const int ocol  = wgin * WCOL + 2 * (tid & 31);
    const int gbrow = g * BSLICE + orow;

    float c0 = cx[gbrow * H_SZ + ocol];
    float c1 = cx[gbrow * H_SZ + ocol + 1];
    float h0 = hx[gbrow * H_SZ + ocol];
    float h1 = hx[gbrow * H_SZ + ocol + 1];

    unsigned* myflag = flags + g * 64 + wgin * 8 + wid;

    // ---- publish h(0) into buffer 0; per-wave drain + flag = 1
    {
        _Float16* hb0 = hbuf + (size_t)g * (BSLICE * H_SZ);
        union { _Float16 hp[2]; unsigned u; } pk;
        pk.hp[0] = (_Float16)h0; pk.hp[1] = (_Float16)h1;
        __hip_atomic_store((unsigned*)(hb0 + orow * H_SZ + ocol), pk.u,
                           __ATOMIC_RELAXED, __HIP_MEMORY_SCOPE_AGENT);
    }
    asm volatile("s_waitcnt vmcnt(0)" ::: "memory");
    if (lane == 0)
        __hip_atomic_store(myflag, 1u, __ATOMIC_RELAXED, __HIP_MEMORY_SCOPE_AGENT);

    #pragma unroll 1
    for (int t = 0; t < T_STEPS; ++t) {
        // -- x_t @ W_ih^T + bias (h-independent; loads overlap the poll)
        f32x4 acc[2];
        #pragma unroll
        for (int r = 0; r < 4; ++r) {
            const int grow = g * BSLICE + fr_kg * 4 + r;
            const f32x2* xp = (const f32x2*)(x + ((size_t)t * B_SZ + grow) * I_SZ);
            const f32x2 a0 = xp[0], a1 = xp[1], a2 = xp[2], a3 = xp[3], a4 = xp[4];
            #pragma unroll
            for (int f = 0; f < 2; ++f) {
                float s = bias[f];
                s += a0.x*wih[f][0] + a0.y*wih[f][1] + a1.x*wih[f][2] + a1.y*wih[f][3]
                   + a2.x*wih[f][4] + a2.y*wih[f][5] + a3.x*wih[f][6] + a3.y*wih[f][7]
                   + a4.x*wih[f][8] + a4.y*wih[f][9];
                acc[f][r] = s;
            }
        }

        // -- parallel poll: every wave checks all 64 per-wave flags (4 lines)
        {
            const unsigned tgt = (unsigned)(t + 1);
            const unsigned* fp = flags + g * 64 + lane;
            for (;;) {
                unsigned fv = __hip_atomic_load(fp, __ATOMIC_RELAXED,
                                                __HIP_MEMORY_SCOPE_AGENT);
                if (__all(fv >= tgt)) break;
                __builtin_amdgcn_s_sleep(1);
            }
        }

        // -- coalesced staging: wave stages rows 2*wid, 2*wid+1 (2KB);
        //    each instruction = 64 lanes x 16B = 1KB contiguous.
        {
            const _Float16* hb = hbuf + ((size_t)(t & 1) * NGRP + g) * (BSLICE * H_SZ);
            const char* sp = (const char*)hb + wid * 2048 + lane * 16;
            u32x4 qa, qb;
            asm volatile(
                "global_load_dwordx4 %0, %2, off sc0 sc1\n\t"
                "global_load_dwordx4 %1, %2, off offset:1024 sc0 sc1\n\t"
                "s_waitcnt vmcnt(0)"
                : "=&v"(qa), "=&v"(qb) : "v"(sp) : "memory");
            *(u32x4*)&h_stage[2 * wid][lane * 8]     = qa;
            *(u32x4*)&h_stage[2 * wid + 1][lane * 8] = qb;
        }
        __syncthreads();   // B1: staging visible

        // -- 16 K-chunks: ds_read A-frag, 2 MFMAs each
        #pragma unroll
        for (int c = 0; c < 16; ++c) {
            const f16x8 a = *(const f16x8*)&h_stage[fr_col][c * 32 + fr_kg * 8];
            acc[0] = __builtin_amdgcn_mfma_f32_16x16x32_f16(a, wf[0][c], acc[0], 0, 0, 0);
            acc[1] = __builtin_amdgcn_mfma_f32_16x16x32_f16(a, wf[1][c], acc[1], 0, 0, 0);
        }

        // -- gate pre-activations -> LDS
        #pragma unroll
        for (int f = 0; f < 2; ++f)
            #pragma unroll
            for (int r = 0; r < 4; ++r)
                lds_g[gcL[f]][fr_kg * 4 + r] = acc[f][r];
        __syncthreads();   // B2: gates visible; fences all h_stage reads

        // -- c/h update for 2 owned cells; publish h(t+1); per-wave release
        {
            const int cl = 2 * (tid & 31);
            const float i0 = lds_g[0 * WCOL + cl][orow],     f0 = lds_g[1 * WCOL + cl][orow];
            const float g0 = lds_g[2 * WCOL + cl][orow],     o0 = lds_g[3 * WCOL + cl][orow];
            const float i1 = lds_g[0 * WCOL + cl + 1][orow], f1 = lds_g[1 * WCOL + cl + 1][orow];
            const float g1 = lds_g[2 * WCOL + cl + 1][orow], o1 = lds_g[3 * WCOL + cl + 1][orow];

            const float ig0 = 1.f / (1.f + __expf(-i0));
            const float fg0 = 1.f / (1.f + __expf(-f0));
            const float eg0 = __expf(-2.f * g0);
            const float tg0 = (1.f - eg0) / (1.f + eg0);
            const float og0 = 1.f / (1.f + __expf(-o0));
            const float ig1 = 1.f / (1.f + __expf(-i1));
            const float fg1 = 1.f / (1.f + __expf(-f1));
            const float eg1 = __expf(-2.f * g1);
            const float tg1 = (1.f - eg1) / (1.f + eg1);
            const float og1 = 1.f / (1.f + __expf(-o1));

            c0 = fg0 * c0 + ig0 * tg0;
            c1 = fg1 * c1 + ig1 * tg1;
            const float e0 = __expf(-2.f * c0), e1 = __expf(-2.f * c1);
            h0 = og0 * (1.f - e0) / (1.f + e0);
            h1 = og1 * (1.f - e1) / (1.f + e1);

            if (t < T_STEPS - 1) {
                _Float16* hbn = hbuf + ((size_t)((t + 1) & 1) * NGRP + g)
                                        * (BSLICE * H_SZ);
                union { _Float16 hp[2]; unsigned u; } pk;
                pk.hp[0] = (_Float16)h0; pk.hp[1] = (_Float16)h1;
                __hip_atomic_store((unsigned*)(hbn + orow * H_SZ + ocol), pk.u,
                                   __ATOMIC_RELAXED, __HIP_MEMORY_SCOPE_AGENT);
                // per-WAVE release: drain own stores, then own flag. No barrier.
                asm volatile("s_waitcnt vmcnt(0)" ::: "memory");
                if (lane == 0)
                    __hip_atomic_store(myflag, (unsigned)(t + 2),
                                       __ATOMIC_RELAXED, __HIP_MEMORY_SCOPE_AGENT);
            }
        }
    }

    // ---- outputs: (h, h, c), each [B,H] f32
    out[gbrow * H_SZ + ocol]                       = h0;
    out[gbrow * H_SZ + ocol + 1]                   = h1;
    out[B_SZ * H_SZ + gbrow * H_SZ + ocol]         = h0;
    out[B_SZ * H_SZ + gbrow * H_SZ + ocol + 1]     = h1;
    out[2 * B_SZ * H_SZ + gbrow * H_SZ + ocol]     = c0;
    out[2 * B_SZ * H_SZ + gbrow * H_SZ + ocol + 1] = c1;
}

extern "C" void kernel_launch(void* const* d_in, const int* in_sizes, int n_in,
                              void* d_out, int out_size, void* d_ws, size_t ws_size,
                              hipStream_t stream) {
    const float* x    = (const float*)d_in[0];
    const float* hx   = (const float*)d_in[1];
    const float* cx   = (const float*)d_in[2];
    const float* W_ih = (const float*)d_in[3];
    const float* W_hh = (const float*)d_in[4];
    const float* b_ih = (const float*)d_in[5];
    const float* b_hh = (const float*)d_in[6];
    float* out = (float*)d_out;

    // ws: [0,2048) flags ; [4096, 4096+256K) fp16 h double-buffer
    char* ws = (char*)d_ws;
    unsigned* flags = (unsigned*)ws;
    _Float16* hbuf  = (_Float16*)(ws + 4096);

    clear_flags_kernel<<<2, 256, 0, stream>>>(flags);
    lstm_persistent<<<NWG, NTHR, 0, stream>>>(x, hx, cx, W_ih, W_hh, b_ih, b_hh,
                                              out, flags, hbuf);
}

// Round 13
// 6493.930 us; speedup vs baseline: 2.8700x; 1.5668x over previous
//
#include <hip/hip_runtime.h>
#include <hip/hip_fp16.h>

#define T_STEPS 2048
#define B_SZ 128
#define I_SZ 10
#define H_SZ 512

#define NGRP 8            // batch groups (16 rows each)
#define GWG 8             // wgs per group
#define NWG (NGRP * GWG)  // 64 workgroups
#define BSLICE 16         // batch rows per group
#define WCOL 64           // hidden cols per wg
#define NTHR 512

typedef _Float16 f16x8 __attribute__((ext_vector_type(8)));
typedef float f32x4 __attribute__((ext_vector_type(4)));
typedef float f32x2 __attribute__((ext_vector_type(2)));
typedef unsigned u32x4 __attribute__((ext_vector_type(4)));
typedef unsigned u32x2 __attribute__((ext_vector_type(2)));
typedef unsigned long long u64t;

// Tagged h buffers: [2][NGRP][BSLICE][H/2] u64, u64 = (tag << 32) | 2xfp16.
// MUST be zeroed before every persistent launch (stale tags / 0xAA poison
// would satisfy the tag check).
__global__ void clear_hbuf_kernel(u64t* p) {
    const int i = blockIdx.x * 256 + threadIdx.x;   // 16384 threads
    #pragma unroll
    for (int k = 0; k < 4; ++k)
        __hip_atomic_store(p + i + k * 16384, 0ull,
                           __ATOMIC_RELAXED, __HIP_MEMORY_SCOPE_AGENT);
}

// Persistent LSTM: tagged-payload publish (fire-and-forget, NO producer
// drain/flag) + SENTINEL pre-spin (cheap detection, NO sweep retries).
//
//   8 independent batch-groups x 8 wgs; wg owns 64 hidden cols (all 4 gates,
//   full K) of its group's 16 batch rows. W_hh fp16 register-resident.
//
//   publish: each thread stores ONE tagged u64 {tag=t+2 | 2xfp16} with a
//   relaxed agent-scope atomic (sc0 sc1, coherent at LLC). No vmcnt drain,
//   no flag array, no release barrier — the store IS the signal.
//   consume: wave0 spins on 8 SENTINEL granules (the u64 written by thread
//   511 of each producer wg: row 15, last col-pair of its 64-col slice) —
//   8B per lane per retry, as cheap as R8's flag poll but the sentinel
//   lands ~1us earlier (no drain before it). Then ONE coalesced sweep
//   (1KB contiguous per instruction) with per-granule tag validation;
//   stale granules (rare: store-landing skew) re-read exec-masked.
//   Correctness rests on per-granule tags only, never on sentinels.
//
// Double-buffer safety (proven in R9/R10): publish at end of step s writes
// tag s+2 into buf[(s+1)&1]; overwriting buf[p] again requires every wg to
// have completed staging(t) reads of buf[p], enforced by the tag chain.
// Intra-8B atomicity: one store per granule; no torn tag/payload.
//
// LDS hazards: h_stage sweep-writes(t+1) vs MFMA reads(t): separated by
// B2(t) + spinB(t+1). own-tile write(t) precedes spinB(t+1) < B1(t+1) <
// all t+1 reads. lds_g writes(t+1) (post-B1(t+1)) vs update reads(t)
// (post-B2(t)): separated by spinB/B1 of t+1.
__global__ __launch_bounds__(NTHR, 2) void lstm_persistent(
    const float* __restrict__ x,     // [T,B,I]
    const float* __restrict__ hx,    // [B,H]
    const float* __restrict__ cx,    // [B,H]
    const float* __restrict__ W_ih,  // [4H,I]
    const float* __restrict__ W_hh,  // [4H,H]
    const float* __restrict__ b_ih,  // [4H]
    const float* __restrict__ b_hh,  // [4H]
    float* __restrict__ out,         // [3*B*H] = h, h, c
    u64t* hbuf)                      // [2][NGRP][BSLICE][H/2] tagged
{
    __shared__ _Float16 h_stage[BSLICE][520];   // row stride 1040B
    __shared__ float lds_g[4 * WCOL][17];       // [gate*64+col][row], padded

    const int wg   = blockIdx.x;
    const int g    = wg >> 3;          // batch group 0..7
    const int wgin = wg & 7;           // wg within group 0..7
    const int tid  = threadIdx.x;
    const int wid  = tid >> 6;         // wave 0..7
    const int lane = tid & 63;
    const int fr_col = lane & 15;
    const int fr_kg  = lane >> 4;      // 0..3

    // ---- this wave's two gate-column fragments (wg covers 256 gate-cols)
    int gcL[2], wr[2];
    #pragma unroll
    for (int f = 0; f < 2; ++f) {
        gcL[f] = wid * 32 + f * 16 + fr_col;              // 0..255
        wr[f]  = (gcL[f] >> 6) * H_SZ + wgin * WCOL + (gcL[f] & 63);
    }

    // ---- W_hh B-fragments: 2 frags x 16 K-chunks, fp16 register-resident
    f16x8 wf[2][16];
    #pragma unroll
    for (int f = 0; f < 2; ++f)
        #pragma unroll
        for (int c = 0; c < 16; ++c) {
            const float* p = W_hh + (size_t)wr[f] * H_SZ + c * 32 + fr_kg * 8;
            f16x8 w;
            #pragma unroll
            for (int e = 0; e < 8; ++e) w[e] = (_Float16)p[e];
            wf[f][c] = w;
        }

    // ---- W_ih rows + combined bias
    float wih[2][I_SZ], bias[2];
    #pragma unroll
    for (int f = 0; f < 2; ++f) {
        #pragma unroll
        for (int i = 0; i < I_SZ; ++i) wih[f][i] = W_ih[wr[f] * I_SZ + i];
        bias[f] = b_ih[wr[f]] + b_hh[wr[f]];
    }

    // ---- owned cells: 2 adjacent per thread (16 rows x 64 cols per wg)
    const int orow  = tid >> 5;                    // 0..15
    const int ocol  = wgin * WCOL + 2 * (tid & 31);
    const int gbrow = g * BSLICE + orow;
    const size_t my_q = (size_t)orow * 256 + (ocol >> 1);   // u64 idx in slice

    float c0 = cx[gbrow * H_SZ + ocol];
    float c1 = cx[gbrow * H_SZ + ocol + 1];
    float h0 = hx[gbrow * H_SZ + ocol];
    float h1 = hx[gbrow * H_SZ + ocol + 1];

    // ---- staging geometry (coalesced): piece j of this lane
    int   st_row[4], st_p[4];
    bool  st_own[4];
    #pragma unroll
    for (int j = 0; j < 4; ++j) {
        const int q = wid * 512 + j * 128 + lane * 2;
        st_row[j] = q >> 8;
        st_p[j]   = q & 255;
        st_own[j] = ((st_p[j] >> 5) == wgin);
    }

    // ---- sentinel for producer wg p = granule (row 15, last col-pair of p)
    //      written by p's thread 511: idx = 15*256 + p*32 + 31
    const int sent_idx = 15 * 256 + (lane & 7) * 32 + 31;

    // ---- publish h(0) with tag 1 into buffer 0 + own-tile LDS write
    {
        u64t* hb0 = hbuf + (size_t)g * (BSLICE * 256);
        union { _Float16 hp[2]; unsigned u; } pk;
        pk.hp[0] = (_Float16)h0; pk.hp[1] = (_Float16)h1;
        __hip_atomic_store(hb0 + my_q, ((u64t)1u << 32) | pk.u,
                           __ATOMIC_RELAXED, __HIP_MEMORY_SCOPE_AGENT);
        *(unsigned*)&h_stage[orow][ocol] = pk.u;
    }

    #pragma unroll 1
    for (int t = 0; t < T_STEPS; ++t) {
        // -- x_t @ W_ih^T + bias (h-independent; overlaps sentinel landing)
        f32x4 acc[2];
        #pragma unroll
        for (int r = 0; r < 4; ++r) {
            const int grow = g * BSLICE + fr_kg * 4 + r;
            const f32x2* xp = (const f32x2*)(x + ((size_t)t * B_SZ + grow) * I_SZ);
            const f32x2 a0 = xp[0], a1 = xp[1], a2 = xp[2], a3 = xp[3], a4 = xp[4];
            #pragma unroll
            for (int f = 0; f < 2; ++f) {
                float s = bias[f];
                s += a0.x*wih[f][0] + a0.y*wih[f][1] + a1.x*wih[f][2] + a1.y*wih[f][3]
                   + a2.x*wih[f][4] + a2.y*wih[f][5] + a3.x*wih[f][6] + a3.y*wih[f][7]
                   + a4.x*wih[f][8] + a4.y*wih[f][9];
                acc[f][r] = s;
            }
        }

        const u64t* hb = hbuf + ((size_t)(t & 1) * NGRP + g) * (BSLICE * 256);
        const unsigned tgt = (unsigned)(t + 1);

        // -- sentinel spin: wave0 only, 8B/lane/retry (cheap, few lines)
        if (wid == 0) {
            const u64t* sp = hb + sent_idx;
            for (;;) {
                u64t sv = __hip_atomic_load(sp, __ATOMIC_RELAXED,
                                            __HIP_MEMORY_SCOPE_AGENT);
                if (__all((unsigned)(sv >> 32) >= tgt)) break;
                __builtin_amdgcn_s_sleep(1);
            }
        }
        __syncthreads();   // spinB: sentinels fresh for all waves

        // -- ONE coalesced tagged sweep (validate all granule tags; rare
        //    stale granules re-read exec-masked)
        {
            const char* sp = (const char*)hb + wid * 4096 + lane * 16;
            u32x4 q0, q1, q2, q3;
            bool done = false;
            for (;;) {
                if (!done) {
                    asm volatile(
                        "global_load_dwordx4 %0, %4, off sc0 sc1\n\t"
                        "global_load_dwordx4 %1, %4, off offset:1024 sc0 sc1\n\t"
                        "global_load_dwordx4 %2, %4, off offset:2048 sc0 sc1\n\t"
                        "global_load_dwordx4 %3, %4, off offset:3072 sc0 sc1\n\t"
                        "s_waitcnt vmcnt(0)"
                        : "=&v"(q0), "=&v"(q1), "=&v"(q2), "=&v"(q3)
                        : "v"(sp) : "memory");
                    done = (st_own[0] || (q0.y >= tgt && q0.w >= tgt)) &&
                           (st_own[1] || (q1.y >= tgt && q1.w >= tgt)) &&
                           (st_own[2] || (q2.y >= tgt && q2.w >= tgt)) &&
                           (st_own[3] || (q3.y >= tgt && q3.w >= tgt));
                }
                if (__all(done)) break;
                __builtin_amdgcn_s_sleep(1);
            }
            if (!st_own[0]) *(u32x2*)&h_stage[st_row[0]][st_p[0] * 2] = (u32x2){q0.x, q0.z};
            if (!st_own[1]) *(u32x2*)&h_stage[st_row[1]][st_p[1] * 2] = (u32x2){q1.x, q1.z};
            if (!st_own[2]) *(u32x2*)&h_stage[st_row[2]][st_p[2] * 2] = (u32x2){q2.x, q2.z};
            if (!st_own[3]) *(u32x2*)&h_stage[st_row[3]][st_p[3] * 2] = (u32x2){q3.x, q3.z};
        }
        __syncthreads();   // B1: staging visible

        // -- 16 K-chunks: ds_read A-frag, 2 MFMAs each
        #pragma unroll
        for (int c = 0; c < 16; ++c) {
            const f16x8 a = *(const f16x8*)&h_stage[fr_col][c * 32 + fr_kg * 8];
            acc[0] = __builtin_amdgcn_mfma_f32_16x16x32_f16(a, wf[0][c], acc[0], 0, 0, 0);
            acc[1] = __builtin_amdgcn_mfma_f32_16x16x32_f16(a, wf[1][c], acc[1], 0, 0, 0);
        }

        // -- gate pre-activations -> LDS
        #pragma unroll
        for (int f = 0; f < 2; ++f)
            #pragma unroll
            for (int r = 0; r < 4; ++r)
                lds_g[gcL[f]][fr_kg * 4 + r] = acc[f][r];
        __syncthreads();   // B2: gates visible; fences all h_stage reads

        // -- c/h update; fire-and-forget tagged publish + own-tile shortcut
        {
            const int cl = 2 * (tid & 31);
            const float i0 = lds_g[0 * WCOL + cl][orow],     f0 = lds_g[1 * WCOL + cl][orow];
            const float g0 = lds_g[2 * WCOL + cl][orow],     o0 = lds_g[3 * WCOL + cl][orow];
            const float i1 = lds_g[0 * WCOL + cl + 1][orow], f1 = lds_g[1 * WCOL + cl + 1][orow];
            const float g1 = lds_g[2 * WCOL + cl + 1][orow], o1 = lds_g[3 * WCOL + cl + 1][orow];

            const float ig0 = 1.f / (1.f + __expf(-i0));
            const float fg0 = 1.f / (1.f + __expf(-f0));
            const float eg0 = __expf(-2.f * g0);
            const float tg0 = (1.f - eg0) / (1.f + eg0);
            const float og0 = 1.f / (1.f + __expf(-o0));
            const float ig1 = 1.f / (1.f + __expf(-i1));
            const float fg1 = 1.f / (1.f + __expf(-f1));
            const float eg1 = __expf(-2.f * g1);
            const float tg1 = (1.f - eg1) / (1.f + eg1);
            const float og1 = 1.f / (1.f + __expf(-o1));

            c0 = fg0 * c0 + ig0 * tg0;
            c1 = fg1 * c1 + ig1 * tg1;
            const float e0 = __expf(-2.f * c0), e1 = __expf(-2.f * c1);
            h0 = og0 * (1.f - e0) / (1.f + e0);
            h1 = og1 * (1.f - e1) / (1.f + e1);

            if (t < T_STEPS - 1) {
                u64t* hbn = hbuf + ((size_t)((t + 1) & 1) * NGRP + g) * (BSLICE * 256);
                union { _Float16 hp[2]; unsigned u; } pk;
                pk.hp[0] = (_Float16)h0; pk.hp[1] = (_Float16)h1;
                __hip_atomic_store(hbn + my_q,
                                   ((u64t)(unsigned)(t + 2) << 32) | pk.u,
                                   __ATOMIC_RELAXED, __HIP_MEMORY_SCOPE_AGENT);
                *(unsigned*)&h_stage[orow][ocol] = pk.u;   // own-tile shortcut
            }
        }
    }

    // ---- outputs: (h, h, c), each [B,H] f32
    out[gbrow * H_SZ + ocol]                       = h0;
    out[gbrow * H_SZ + ocol + 1]                   = h1;
    out[B_SZ * H_SZ + gbrow * H_SZ + ocol]         = h0;
    out[B_SZ * H_SZ + gbrow * H_SZ + ocol + 1]     = h1;
    out[2 * B_SZ * H_SZ + gbrow * H_SZ + ocol]     = c0;
    out[2 * B_SZ * H_SZ + gbrow * H_SZ + ocol + 1] = c1;
}

extern "C" void kernel_launch(void* const* d_in, const int* in_sizes, int n_in,
                              void* d_out, int out_size, void* d_ws, size_t ws_size,
                              hipStream_t stream) {
    const float* x    = (const float*)d_in[0];
    const float* hx   = (const float*)d_in[1];
    const float* cx   = (const float*)d_in[2];
    const float* W_ih = (const float*)d_in[3];
    const float* W_hh = (const float*)d_in[4];
    const float* b_ih = (const float*)d_in[5];
    const float* b_hh = (const float*)d_in[6];
    float* out = (float*)d_out;

    // ws: [0, 512KB) tagged h double-buffer
    u64t* hbuf = (u64t*)d_ws;

    clear_hbuf_kernel<<<64, 256, 0, stream>>>(hbuf);
    lstm_persistent<<<NWG, NTHR, 0, stream>>>(x, hx, cx, W_ih, W_hh, b_ih, b_hh,
                                              out, hbuf);
}